// Round 5
// baseline (200.188 us; speedup 1.0000x reference)
//
#include <hip/hip_runtime.h>
#include <hip/hip_bf16.h>
#include <stdint.h>

typedef unsigned short u16;
typedef __attribute__((ext_vector_type(8))) short short8;
typedef __attribute__((ext_vector_type(4))) float floatx4;

#define N_IMG 4
#define C_IN  2048
#define HW    1024
#define KK    9
#define O_OUT 256
#define NPIX  4096          // N_IMG*HW
#define M_ROWS 2385         // 2304 proj rows + 81 conv rows
#define M_PAD  2432         // 19*128
#define K_DIM  2048
#define BN_EPS 1e-5f

// workspace offsets (bytes), all 256-aligned
#define OFF_A    0u
#define OFF_XT   9961472u          // A: 2432*2048*2
#define OFF_H    26738688u         // XT: 4096*2048*2

// fp32 -> bf16 bits, round-to-nearest-even
__device__ __forceinline__ u16 f2b(float f) {
    unsigned u = __float_as_uint(f);
    return (u16)((u + 0x7FFFu + ((u >> 16) & 1u)) >> 16);
}
__device__ __forceinline__ float b2f(u16 h) {
    return __uint_as_float(((unsigned)h) << 16);
}

// load 8 consecutive fp32 elements (eidx multiple of 8) as bf16 bits
__device__ __forceinline__ void load8f(const float* base, size_t eidx, u16* out) {
    const float* p = base + eidx;
    float4 a = ((const float4*)p)[0];
    float4 b = ((const float4*)p)[1];
    float f[8] = {a.x, a.y, a.z, a.w, b.x, b.y, b.z, b.w};
#pragma unroll
    for (int j = 0; j < 8; ++j) out[j] = f2b(f[j]);
}

// ---------------- merged staging kernel ----------------
// blocks [0,2048): transpose x (N,C,H,W) fp32 -> XT (n*HW+p, c) bf16
// blocks [2048,2304): A proj rows from weight
// blocks [2304,2313): A conv rows from conv_w
// block  2313: zero-pad A rows 2385..2431
__global__ void build_all(const float* __restrict__ x, const float* __restrict__ wgt,
                          const float* __restrict__ cw, u16* __restrict__ xt,
                          u16* __restrict__ A) {
    __shared__ __align__(16) u16 lds[9 * 2056];
    int b = blockIdx.x, t = threadIdx.x;
    if (b < 2048) {
        int c0 = (b & 31) * 64, p0 = ((b >> 5) & 15) * 64, n = b >> 9;
        int r = t >> 3, pv = (t & 7) * 8;
        u16 h0[8], h1[8];
        load8f(x, (size_t)(n * C_IN + c0 + r) * HW + p0 + pv, h0);
        load8f(x, (size_t)(n * C_IN + c0 + r + 32) * HW + p0 + pv, h1);
#pragma unroll
        for (int j = 0; j < 8; ++j) {
            lds[(pv + j) * 72 + r]      = h0[j];
            lds[(pv + j) * 72 + r + 32] = h1[j];
        }
        __syncthreads();
        int pr = t >> 3, cv = (t & 7) * 8;
        uint4 o0 = *(const uint4*)&lds[pr * 72 + cv];
        uint4 o1 = *(const uint4*)&lds[(pr + 32) * 72 + cv];
        *(uint4*)(xt + (size_t)(n * HW + p0 + pr) * K_DIM + c0 + cv) = o0;
        *(uint4*)(xt + (size_t)(n * HW + p0 + pr + 32) * K_DIM + c0 + cv) = o1;
    } else if (b < 2304) {
        int o = b - 2048;
        size_t base = (size_t)o * 18432;   // weight[o][c][l], e = c*9+l
        for (int i = 0; i < 9; ++i) {
            int e0 = (t + i * 256) * 8;
            u16 hv[8];
            load8f(wgt, base + e0, hv);
#pragma unroll
            for (int j = 0; j < 8; ++j) {
                int e = e0 + j;
                int c = e / 9, l = e - c * 9;
                lds[l * 2056 + c] = hv[j];
            }
        }
        __syncthreads();
        for (int l = 0; l < 9; ++l) {
            size_t row = (size_t)l * 256 + o;
            *(uint4*)(A + row * K_DIM + t * 8) = *(const uint4*)&lds[l * 2056 + t * 8];
        }
    } else if (b < 2313) {
        int l = b - 2304;
        size_t base = (size_t)l * 18432;    // conv_w[l][c][k], e = c*9+k
        for (int i = 0; i < 9; ++i) {
            int e0 = (t + i * 256) * 8;
            u16 hv[8];
            load8f(cw, base + e0, hv);
#pragma unroll
            for (int j = 0; j < 8; ++j) {
                int e = e0 + j;
                int c = e / 9, k = e - c * 9;
                lds[k * 2056 + c] = hv[j];
            }
        }
        __syncthreads();
        for (int k = 0; k < 9; ++k) {
            size_t row = 2304 + (size_t)k * 9 + l;
            *(uint4*)(A + row * K_DIM + t * 8) = *(const uint4*)&lds[k * 2056 + t * 8];
        }
    } else {
        uint4 z = {0, 0, 0, 0};
        uint4* dst = (uint4*)(A + (size_t)2385 * K_DIM);
        for (int i = t; i < (47 * 2048) / 8; i += 256) dst[i] = z;
    }
}

// ---------------- GEMM: H (M_PAD x NPIX) = A * XT^T, 128x128 tiles (R3 config) ----------------
__device__ __forceinline__ void gload_lds16(const void* g, void* l) {
    __builtin_amdgcn_global_load_lds((__attribute__((address_space(1))) void*)(g),
                                     (__attribute__((address_space(3))) void*)(l), 16, 0, 0);
}

__global__ void gemm_bt(const u16* __restrict__ A, const u16* __restrict__ B,
                        __hip_bfloat16* __restrict__ C) {
    __shared__ __align__(16) u16 As[128 * 32];
    __shared__ __align__(16) u16 Bs[128 * 32];
    int bx = blockIdx.x;
    int mt = bx % 19, nt = bx / 19;
    int m0 = mt * 128, n0 = nt * 128;
    int t = threadIdx.x;
    int w = t >> 6, lam = t & 63;
    int wm = w >> 1, wn = w & 1;
    int lm = lam & 15, q = lam >> 4;

    floatx4 acc[4][4];
    floatx4 z = {0.f, 0.f, 0.f, 0.f};
#pragma unroll
    for (int i = 0; i < 4; ++i)
#pragma unroll
        for (int j = 0; j < 4; ++j) acc[i][j] = z;

    int c0 = w, c1 = w + 4;                 // LDS chunk ids (wave-uniform)
    int rrow0 = c0 * 16 + (lam >> 2);
    int rrow1 = c1 * 16 + (lam >> 2);
    int kc = (lam & 3) * 8;
    const u16* gA0 = A + (size_t)(m0 + rrow0) * K_DIM + kc;
    const u16* gA1 = A + (size_t)(m0 + rrow1) * K_DIM + kc;
    const u16* gB0 = B + (size_t)(n0 + rrow0) * K_DIM + kc;
    const u16* gB1 = B + (size_t)(n0 + rrow1) * K_DIM + kc;
    u16* lA0 = As + c0 * 512;  u16* lA1 = As + c1 * 512;
    u16* lB0 = Bs + c0 * 512;  u16* lB1 = Bs + c1 * 512;

    for (int kt = 0; kt < K_DIM / 32; ++kt) {
        gload_lds16(gA0, lA0);
        gload_lds16(gA1, lA1);
        gload_lds16(gB0, lB0);
        gload_lds16(gB1, lB1);
        gA0 += 32; gA1 += 32; gB0 += 32;  gB1 += 32;
        __syncthreads();
        short8 af[4], bf[4];
#pragma unroll
        for (int i = 0; i < 4; ++i)
            af[i] = *(const short8*)(As + (wm * 64 + i * 16 + lm) * 32 + q * 8);
#pragma unroll
        for (int j = 0; j < 4; ++j)
            bf[j] = *(const short8*)(Bs + (wn * 64 + j * 16 + lm) * 32 + q * 8);
#pragma unroll
        for (int i = 0; i < 4; ++i)
#pragma unroll
            for (int j = 0; j < 4; ++j)
                acc[i][j] = __builtin_amdgcn_mfma_f32_16x16x32_bf16(af[i], bf[j], acc[i][j], 0, 0, 0);
        __syncthreads();
    }
    // C/D layout: col=lane&15, row=(lane>>4)*4+reg
#pragma unroll
    for (int i = 0; i < 4; ++i) {
        int gm = m0 + wm * 64 + i * 16 + q * 4;
#pragma unroll
        for (int j = 0; j < 4; ++j) {
            int gn = n0 + wn * 64 + j * 16 + lm;
#pragma unroll
            for (int r = 0; r < 4; ++r)
                C[(size_t)(gm + r) * NPIX + gn] = __float2bfloat16(acc[i][j][r]);
        }
    }
}

// ---------------- fused tail: BN stats (redundant/block) + softmax + dynamic-weighted projection ----------------
// grid 64 blocks x 256 thr: block b -> n = b>>4, pixel chunk pc = (b>>2)&3, out-channel chunk oc = b&3
__global__ void tail_fused(const __hip_bfloat16* __restrict__ Hm, const float* __restrict__ gamma,
                           const float* __restrict__ beta, float* __restrict__ out) {
    __shared__ float redbuf[4][18];
    __shared__ float statS[18];
    int b = blockIdx.x;
    int nb = b >> 4, pc = (b >> 2) & 3, oc = b & 3;
    int t = threadIdx.x;

    // ---- phase A: full BN stats over all (n,l,pix), redundantly per block ----
    float s1[9], s2[9];
#pragma unroll
    for (int l = 0; l < 9; ++l) { s1[l] = 0.f; s2[l] = 0.f; }
    for (int n = 0; n < 4; ++n) {
        for (int i = 0; i < 4; ++i) {
            int pix = i * 256 + t;
            int y = pix >> 5, x = pix & 31;
            float v[9];
#pragma unroll
            for (int l = 0; l < 9; ++l) v[l] = 0.f;
#pragma unroll
            for (int k = 0; k < 9; ++k) {
                int dy = k / 3 - 1, dx = k % 3 - 1;
                int yy = y + dy, xx = x + dx;
                bool ok = (yy >= 0 && yy < 32 && xx >= 0 && xx < 32);
                int sp = ok ? (pix + dy * 32 + dx) : pix;
                float m = ok ? 1.f : 0.f;
                const __hip_bfloat16* base = Hm + (size_t)(2304 + k * 9) * NPIX + n * HW + sp;
#pragma unroll
                for (int l = 0; l < 9; ++l)
                    v[l] += m * __bfloat162float(base[(size_t)l * NPIX]);
            }
#pragma unroll
            for (int l = 0; l < 9; ++l) { s1[l] += v[l]; s2[l] += v[l] * v[l]; }
        }
    }
#pragma unroll
    for (int l = 0; l < 9; ++l) {
        for (int off = 32; off > 0; off >>= 1) {
            s1[l] += __shfl_down(s1[l], off, 64);
            s2[l] += __shfl_down(s2[l], off, 64);
        }
    }
    int wv = t >> 6, lane = t & 63;
    if (lane == 0) {
#pragma unroll
        for (int l = 0; l < 9; ++l) { redbuf[wv][l] = s1[l]; redbuf[wv][9 + l] = s2[l]; }
    }
    __syncthreads();
    if (t < 18) statS[t] = redbuf[0][t] + redbuf[1][t] + redbuf[2][t] + redbuf[3][t];
    __syncthreads();

    // ---- phase B: this thread's pixel -> BN + softmax (sig in registers) ----
    int pix = pc * 256 + t;
    int y = pix >> 5, x = pix & 31;
    float v[9];
#pragma unroll
    for (int l = 0; l < 9; ++l) v[l] = 0.f;
#pragma unroll
    for (int k = 0; k < 9; ++k) {
        int dy = k / 3 - 1, dx = k % 3 - 1;
        int yy = y + dy, xx = x + dx;
        bool ok = (yy >= 0 && yy < 32 && xx >= 0 && xx < 32);
        int sp = ok ? (pix + dy * 32 + dx) : pix;
        float m = ok ? 1.f : 0.f;
        const __hip_bfloat16* base = Hm + (size_t)(2304 + k * 9) * NPIX + nb * HW + sp;
#pragma unroll
        for (int l = 0; l < 9; ++l)
            v[l] += m * __bfloat162float(base[(size_t)l * NPIX]);
    }
    float mx = -1e30f;
#pragma unroll
    for (int l = 0; l < 9; ++l) {
        float mean = statS[l] * (1.f / 4096.f);
        float var  = statS[9 + l] * (1.f / 4096.f) - mean * mean;
        float tv = (v[l] - mean) * rsqrtf(var + BN_EPS);
        tv = tv * gamma[l] + beta[l];
        v[l] = tv; mx = fmaxf(mx, tv);
    }
    float ssum = 0.f;
#pragma unroll
    for (int l = 0; l < 9; ++l) { v[l] = __expf(v[l] - mx); ssum += v[l]; }
    float inv = 1.f / ssum;

    // ---- phase C: out[nb, oc*64+o, pix] = sum_l sig[l] * H[l*256+o, nb*HW+shift(pix,l)] ----
    float sv[9]; int sp[9];
#pragma unroll
    for (int l = 0; l < 9; ++l) {
        int dy = l / 3 - 1, dx = l % 3 - 1;
        int yy = y + dy, xx = x + dx;
        bool ok = (yy >= 0 && yy < 32 && xx >= 0 && xx < 32);
        sp[l] = ok ? (pix + dy * 32 + dx) : pix;
        sv[l] = ok ? v[l] * inv : 0.f;
    }
    const __hip_bfloat16* hb = Hm + (size_t)nb * HW;
    float* ob = out + ((size_t)nb * 256 + oc * 64) * HW + pix;
    for (int o = 0; o < 64; ++o) {
        int oo = oc * 64 + o;
        float acc = 0.f;
#pragma unroll
        for (int l = 0; l < 9; ++l)
            acc += sv[l] * __bfloat162float(hb[(size_t)(l * 256 + oo) * NPIX + sp[l]]);
        ob[(size_t)o * HW] = acc;
    }
}

extern "C" void kernel_launch(void* const* d_in, const int* in_sizes, int n_in,
                              void* d_out, int out_size, void* d_ws, size_t ws_size,
                              hipStream_t stream) {
    const float* x     = (const float*)d_in[0];
    const float* cw    = (const float*)d_in[1];
    const float* gamma = (const float*)d_in[2];
    const float* beta  = (const float*)d_in[3];
    const float* wgt   = (const float*)d_in[4];

    char* ws = (char*)d_ws;
    u16* Abuf = (u16*)(ws + OFF_A);
    u16* XT   = (u16*)(ws + OFF_XT);
    u16* Hm   = (u16*)(ws + OFF_H);

    build_all<<<2314, 256, 0, stream>>>(x, wgt, cw, XT, Abuf);
    gemm_bt<<<19 * 32, 256, 0, stream>>>(Abuf, XT, (__hip_bfloat16*)Hm);
    tail_fused<<<64, 256, 0, stream>>>((const __hip_bfloat16*)Hm, gamma, beta, (float*)d_out);
}

// Round 7
// 176.671 us; speedup vs baseline: 1.1331x; 1.1331x over previous
//
#include <hip/hip_runtime.h>
#include <hip/hip_bf16.h>
#include <stdint.h>

typedef unsigned short u16;
typedef __attribute__((ext_vector_type(8))) short short8;
typedef __attribute__((ext_vector_type(4))) float floatx4;

#define N_IMG 4
#define C_IN  2048
#define HW    1024
#define KK    9
#define O_OUT 256
#define NPIX  4096          // N_IMG*HW
#define M_PAD  2432         // 19*128 (2304 proj rows + 81 conv + pad)
#define K_DIM  2048
#define BN_EPS 1e-5f

// workspace offsets (bytes), 256-aligned
#define OFF_A    0u
#define OFF_XT   9961472u          // A: 2432*2048*2
#define OFF_H    26738688u         // XT: 4096*2048*2
#define OFF_SRAW 46661632u         // H: 2432*4096*2
#define OFF_STAT 46809088u         // sraw: 36864*4

// fp32 -> bf16 bits, round-to-nearest-even
__device__ __forceinline__ u16 f2b(float f) {
    unsigned u = __float_as_uint(f);
    return (u16)((u + 0x7FFFu + ((u >> 16) & 1u)) >> 16);
}

__device__ __forceinline__ void load8f(const float* base, size_t eidx, u16* out) {
    const float* p = base + eidx;
    float4 a = ((const float4*)p)[0];
    float4 b = ((const float4*)p)[1];
    float f[8] = {a.x, a.y, a.z, a.w, b.x, b.y, b.z, b.w};
#pragma unroll
    for (int j = 0; j < 8; ++j) out[j] = f2b(f[j]);
}

// ---------------- merged staging kernel (validated R4 config) ----------------
// blocks [0,2048): transpose x (N,C,H,W) fp32 -> XT (n*HW+p, c) bf16
// blocks [2048,2304): A proj rows from weight
// blocks [2304,2313): A conv rows from conv_w
// block  2313: zero-pad A rows 2385..2431 + zero stats
__global__ void build_all(const float* __restrict__ x, const float* __restrict__ wgt,
                          const float* __restrict__ cw, u16* __restrict__ xt,
                          u16* __restrict__ A, float* __restrict__ stats) {
    __shared__ __align__(16) u16 lds[9 * 2056];
    int b = blockIdx.x, t = threadIdx.x;
    if (b < 2048) {
        int c0 = (b & 31) * 64, p0 = ((b >> 5) & 15) * 64, n = b >> 9;
        int r = t >> 3, pv = (t & 7) * 8;
        u16 h0[8], h1[8];
        load8f(x, (size_t)(n * C_IN + c0 + r) * HW + p0 + pv, h0);
        load8f(x, (size_t)(n * C_IN + c0 + r + 32) * HW + p0 + pv, h1);
#pragma unroll
        for (int j = 0; j < 8; ++j) {
            lds[(pv + j) * 72 + r]      = h0[j];
            lds[(pv + j) * 72 + r + 32] = h1[j];
        }
        __syncthreads();
        int pr = t >> 3, cv = (t & 7) * 8;
        uint4 o0 = *(const uint4*)&lds[pr * 72 + cv];
        uint4 o1 = *(const uint4*)&lds[(pr + 32) * 72 + cv];
        *(uint4*)(xt + (size_t)(n * HW + p0 + pr) * K_DIM + c0 + cv) = o0;
        *(uint4*)(xt + (size_t)(n * HW + p0 + pr + 32) * K_DIM + c0 + cv) = o1;
    } else if (b < 2304) {
        int o = b - 2048;
        size_t base = (size_t)o * 18432;   // weight[o][c][l], e = c*9+l
        for (int i = 0; i < 9; ++i) {
            int e0 = (t + i * 256) * 8;
            u16 hv[8];
            load8f(wgt, base + e0, hv);
#pragma unroll
            for (int j = 0; j < 8; ++j) {
                int e = e0 + j;
                int c = e / 9, l = e - c * 9;
                lds[l * 2056 + c] = hv[j];
            }
        }
        __syncthreads();
        for (int l = 0; l < 9; ++l) {
            size_t row = (size_t)l * 256 + o;
            *(uint4*)(A + row * K_DIM + t * 8) = *(const uint4*)&lds[l * 2056 + t * 8];
        }
    } else if (b < 2313) {
        int l = b - 2304;
        size_t base = (size_t)l * 18432;    // conv_w[l][c][k], e = c*9+k
        for (int i = 0; i < 9; ++i) {
            int e0 = (t + i * 256) * 8;
            u16 hv[8];
            load8f(cw, base + e0, hv);
#pragma unroll
            for (int j = 0; j < 8; ++j) {
                int e = e0 + j;
                int c = e / 9, k = e - c * 9;
                lds[k * 2056 + c] = hv[j];
            }
        }
        __syncthreads();
        for (int k = 0; k < 9; ++k) {
            size_t row = 2304 + (size_t)k * 9 + l;
            *(uint4*)(A + row * K_DIM + t * 8) = *(const uint4*)&lds[k * 2056 + t * 8];
        }
    } else {
        uint4 z = {0, 0, 0, 0};
        uint4* dst = (uint4*)(A + (size_t)2385 * K_DIM);
        for (int i = t; i < (47 * 2048) / 8; i += 256) dst[i] = z;
        if (t < 18) stats[t] = 0.0f;
    }
}

// ---------------- GEMM: H (M_PAD x NPIX) = A * XT^T, 128x128 tiles (validated config) ----------------
__device__ __forceinline__ void gload_lds16(const void* g, void* l) {
    __builtin_amdgcn_global_load_lds((__attribute__((address_space(1))) void*)(g),
                                     (__attribute__((address_space(3))) void*)(l), 16, 0, 0);
}

__global__ void gemm_bt(const u16* __restrict__ A, const u16* __restrict__ B,
                        __hip_bfloat16* __restrict__ C) {
    __shared__ __align__(16) u16 As[128 * 32];
    __shared__ __align__(16) u16 Bs[128 * 32];
    int bx = blockIdx.x;
    int mt = bx % 19, nt = bx / 19;
    int m0 = mt * 128, n0 = nt * 128;
    int t = threadIdx.x;
    int w = t >> 6, lam = t & 63;
    int wm = w >> 1, wn = w & 1;
    int lm = lam & 15, q = lam >> 4;

    floatx4 acc[4][4];
    floatx4 z = {0.f, 0.f, 0.f, 0.f};
#pragma unroll
    for (int i = 0; i < 4; ++i)
#pragma unroll
        for (int j = 0; j < 4; ++j) acc[i][j] = z;

    int c0 = w, c1 = w + 4;
    int rrow0 = c0 * 16 + (lam >> 2);
    int rrow1 = c1 * 16 + (lam >> 2);
    int kc = (lam & 3) * 8;
    const u16* gA0 = A + (size_t)(m0 + rrow0) * K_DIM + kc;
    const u16* gA1 = A + (size_t)(m0 + rrow1) * K_DIM + kc;
    const u16* gB0 = B + (size_t)(n0 + rrow0) * K_DIM + kc;
    const u16* gB1 = B + (size_t)(n0 + rrow1) * K_DIM + kc;
    u16* lA0 = As + c0 * 512;  u16* lA1 = As + c1 * 512;
    u16* lB0 = Bs + c0 * 512;  u16* lB1 = Bs + c1 * 512;

    for (int kt = 0; kt < K_DIM / 32; ++kt) {
        gload_lds16(gA0, lA0);
        gload_lds16(gA1, lA1);
        gload_lds16(gB0, lB0);
        gload_lds16(gB1, lB1);
        gA0 += 32; gA1 += 32; gB0 += 32; gB1 += 32;
        __syncthreads();
        short8 af[4], bf[4];
#pragma unroll
        for (int i = 0; i < 4; ++i)
            af[i] = *(const short8*)(As + (wm * 64 + i * 16 + lm) * 32 + q * 8);
#pragma unroll
        for (int j = 0; j < 4; ++j)
            bf[j] = *(const short8*)(Bs + (wn * 64 + j * 16 + lm) * 32 + q * 8);
#pragma unroll
        for (int i = 0; i < 4; ++i)
#pragma unroll
            for (int j = 0; j < 4; ++j)
                acc[i][j] = __builtin_amdgcn_mfma_f32_16x16x32_bf16(af[i], bf[j], acc[i][j], 0, 0, 0);
        __syncthreads();
    }
    // C/D layout: col=lane&15, row=(lane>>4)*4+reg
#pragma unroll
    for (int i = 0; i < 4; ++i) {
        int gm = m0 + wm * 64 + i * 16 + q * 4;
#pragma unroll
        for (int j = 0; j < 4; ++j) {
            int gn = n0 + wn * 64 + j * 16 + lm;
#pragma unroll
            for (int r = 0; r < 4; ++r)
                C[(size_t)(gm + r) * NPIX + gn] = __float2bfloat16(acc[i][j][r]);
        }
    }
}

// ---------------- sigma_raw (conv via shifted conv rows of H) + BN stats (validated R4 config) ----------------
__global__ void sigma_stats(const __hip_bfloat16* __restrict__ Hm, float* __restrict__ sraw,
                            float* __restrict__ stats) {
    int b = blockIdx.x;           // (n*9 + l)*4 + quarter
    int qq = b & 3, nl = b >> 2;
    int n = nl / 9, l = nl - n * 9;
    int t = threadIdx.x;
    int pix = qq * 256 + t;
    int y = pix >> 5, x = pix & 31;
    float v = 0.f;
#pragma unroll
    for (int k = 0; k < 9; ++k) {
        int yy = y + k / 3 - 1, xx = x + (k % 3) - 1;
        if (yy >= 0 && yy < 32 && xx >= 0 && xx < 32)
            v += __bfloat162float(Hm[(size_t)(2304 + k * 9 + l) * NPIX + n * HW + yy * 32 + xx]);
    }
    sraw[(size_t)nl * HW + pix] = v;
    __shared__ float r1[256], r2[256];
    r1[t] = v; r2[t] = v * v;
    __syncthreads();
    for (int s = 128; s > 0; s >>= 1) {
        if (t < s) { r1[t] += r1[t + s]; r2[t] += r2[t + s]; }
        __syncthreads();
    }
    if (t == 0) { atomicAdd(&stats[l], r1[0]); atomicAdd(&stats[9 + l], r2[0]); }
}

// ---------------- tail: BN + softmax (register recompute) + dynamic projection ----------------
// grid 1024 blocks: block b -> (n = b>>8, o = b&255); 4 pixels per thread
__global__ void tail(const __hip_bfloat16* __restrict__ Hm, const float* __restrict__ sraw,
                     const float* __restrict__ stats, const float* __restrict__ gamma,
                     const float* __restrict__ beta, float* __restrict__ out) {
    int b = blockIdx.x;
    int n = b >> 8, o = b & 255;
    int t = threadIdx.x;
    float mean[9], istd[9], gg[9], bb[9];
#pragma unroll
    for (int l = 0; l < 9; ++l) {
        float m = stats[l] * (1.f / 4096.f);
        float var = stats[9 + l] * (1.f / 4096.f) - m * m;
        mean[l] = m; istd[l] = rsqrtf(var + BN_EPS);
        gg[l] = gamma[l]; bb[l] = beta[l];
    }
    for (int i = 0; i < 4; ++i) {
        int pix = t + i * 256;
        int y = pix >> 5, x = pix & 31;
        float v[9];
        float mx = -1e30f;
#pragma unroll
        for (int l = 0; l < 9; ++l) {
            float tv = (sraw[(size_t)(n * 9 + l) * HW + pix] - mean[l]) * istd[l];
            tv = tv * gg[l] + bb[l];
            v[l] = tv; mx = fmaxf(mx, tv);
        }
        float ssum = 0.f;
#pragma unroll
        for (int l = 0; l < 9; ++l) { v[l] = __expf(v[l] - mx); ssum += v[l]; }
        float inv = 1.f / ssum;
        float acc = 0.f;
#pragma unroll
        for (int l = 0; l < 9; ++l) {
            int dy = l / 3 - 1, dx = l % 3 - 1;
            int yy = y + dy, xx = x + dx;
            if (yy >= 0 && yy < 32 && xx >= 0 && xx < 32) {
                float h = __bfloat162float(Hm[(size_t)(l * 256 + o) * NPIX + n * HW + yy * 32 + xx]);
                acc += v[l] * inv * h;
            }
        }
        out[((size_t)n * 256 + o) * HW + pix] = acc;
    }
}

extern "C" void kernel_launch(void* const* d_in, const int* in_sizes, int n_in,
                              void* d_out, int out_size, void* d_ws, size_t ws_size,
                              hipStream_t stream) {
    const float* x     = (const float*)d_in[0];
    const float* cw    = (const float*)d_in[1];
    const float* gamma = (const float*)d_in[2];
    const float* beta  = (const float*)d_in[3];
    const float* wgt   = (const float*)d_in[4];

    char* ws = (char*)d_ws;
    u16*   Abuf = (u16*)(ws + OFF_A);
    u16*   XT   = (u16*)(ws + OFF_XT);
    u16*   Hm   = (u16*)(ws + OFF_H);
    float* sraw = (float*)(ws + OFF_SRAW);
    float* stats= (float*)(ws + OFF_STAT);

    build_all<<<2314, 256, 0, stream>>>(x, wgt, cw, XT, Abuf, stats);
    gemm_bt<<<19 * 32, 256, 0, stream>>>(Abuf, XT, (__hip_bfloat16*)Hm);
    sigma_stats<<<N_IMG * KK * 4, 256, 0, stream>>>((const __hip_bfloat16*)Hm, sraw, stats);
    tail<<<N_IMG * O_OUT, 256, 0, stream>>>((const __hip_bfloat16*)Hm, sraw, stats, gamma, beta, (float*)d_out);
}